// Round 11
// baseline (65.179 us; speedup 1.0000x reference)
//
#include <hip/hip_runtime.h>

// ---------------------------------------------------------------------------
// Compile-time wavelet-packet response matrix A[64][50]:
// A[j*8+m][n] = coefficient of x[n] in leaf j, sample m (3-level sym2, zero pad).
// Geometry: 50 -> 26 -> 14 -> 8, pad ph=2 both sides at every level (all even).
// ---------------------------------------------------------------------------
struct Amat { float a[64][50]; };

constexpr Amat makeA() {
    constexpr float h0[4] = { 0.48296291314453416f,  0.8365163037378079f,
                              0.22414386804185735f, -0.12940952255126037f};
    constexpr float h1[4] = {-0.12940952255126037f, -0.22414386804185735f,
                              0.8365163037378079f,  -0.48296291314453416f};
    float L1[2][26][50] = {};
    for (int band = 0; band < 2; ++band)
        for (int m = 0; m < 26; ++m)
            for (int n = 0; n < 50; ++n) {
                int k = n - 2 * m + 2;
                L1[band][m][n] = (k >= 0 && k < 4) ? (band ? h1[k] : h0[k]) : 0.0f;
            }
    float L2[4][14][50] = {};
    for (int j = 0; j < 4; ++j)
        for (int m = 0; m < 14; ++m)
            for (int n = 0; n < 50; ++n) {
                float acc = 0.0f;
                for (int k = 0; k < 4; ++k) {
                    int p = 2 * m + k - 2;
                    if (p >= 0 && p < 26)
                        acc += (j & 1 ? h1[k] : h0[k]) * L1[j >> 1][p][n];
                }
                L2[j][m][n] = acc;
            }
    Amat A = {};
    for (int j = 0; j < 8; ++j)
        for (int m = 0; m < 8; ++m)
            for (int n = 0; n < 50; ++n) {
                float acc = 0.0f;
                for (int k = 0; k < 4; ++k) {
                    int p = 2 * m + k - 2;
                    if (p >= 0 && p < 14)
                        acc += (j & 1 ? h1[k] : h0[k]) * L2[j >> 1][p][n];
                }
                A.a[j * 8 + m][n] = acc;
            }
    return A;
}

__device__ __constant__ Amat cA = makeA();

// ---------------------------------------------------------------------------
// Kernel 1 (1 block): fold W (5x192) + bias into TRANSPOSED padded layout
//   Mgt[k*152 + i] = M[i][k];  Mgt[k*152+150] = bias[k].
// ---------------------------------------------------------------------------
__global__ __launch_bounds__(256) void build_M(const float* __restrict__ W,
                                               const float* __restrict__ bias,
                                               float* __restrict__ Mgt) {
    __shared__ float sW[960];
    const int tid = threadIdx.x;
    #pragma unroll
    for (int t = 0; t < 4; ++t) {
        const int idx = tid + t * 256;
        if (idx < 960) sW[idx] = W[idx];
    }
    __syncthreads();

    if (tid < 150) {
        const int c = tid / 50, n = tid - c * 50;
        float m0 = 0.f, m1 = 0.f, m2 = 0.f, m3 = 0.f, m4 = 0.f;
        #pragma unroll 16
        for (int f = 0; f < 64; ++f) {              // f = j*8 + s
            const float av = cA.a[f][n];
            const int wj = (f >> 3) * 24 + c * 8 + (f & 7);
            m0 = fmaf(sW[0 * 192 + wj], av, m0);
            m1 = fmaf(sW[1 * 192 + wj], av, m1);
            m2 = fmaf(sW[2 * 192 + wj], av, m2);
            m3 = fmaf(sW[3 * 192 + wj], av, m3);
            m4 = fmaf(sW[4 * 192 + wj], av, m4);
        }
        Mgt[0 * 152 + tid] = m0;
        Mgt[1 * 152 + tid] = m1;
        Mgt[2 * 152 + tid] = m2;
        Mgt[3 * 152 + tid] = m3;
        Mgt[4 * 152 + tid] = m4;
    } else if (tid < 155) {
        const int k = tid - 150;
        Mgt[k * 152 + 150] = bias[k];
    } else if (tid < 160) {
        const int k = tid - 155;
        Mgt[k * 152 + 151] = 0.f;
    }
}

// ---------------------------------------------------------------------------
// Kernel 2 — DIAGNOSTIC build (REP=5): R10's gemv, main body repeated REP
// times with runtime-identical values (idempotent stores -> output correct).
// asm-opaque accumulator init + LDS base (rule #17) force real recompute and
// real ds_reads per rep; x loads are deliberately left register-cacheable so
// reps 1..4 isolate the LDS+VALU core. Dispatch > ~50us -> visible in top-5.
// ---------------------------------------------------------------------------
#define REP 5

#define QSTEP(fi)                                                            \
    {   const float2 xv = xr[(fi)];                                          \
        const int ib = base + 2 * (fi);                                      \
        { const float2 mm = *(const float2*)&sMt[0 * 152 + ib];              \
          a0 = fmaf(mm.x, xv.x, a0); a0 = fmaf(mm.y, xv.y, a0); }            \
        { const float2 mm = *(const float2*)&sMt[1 * 152 + ib];              \
          a1 = fmaf(mm.x, xv.x, a1); a1 = fmaf(mm.y, xv.y, a1); }            \
        { const float2 mm = *(const float2*)&sMt[2 * 152 + ib];              \
          a2 = fmaf(mm.x, xv.x, a2); a2 = fmaf(mm.y, xv.y, a2); }            \
        { const float2 mm = *(const float2*)&sMt[3 * 152 + ib];              \
          a3 = fmaf(mm.x, xv.x, a3); a3 = fmaf(mm.y, xv.y, a3); }            \
        { const float2 mm = *(const float2*)&sMt[4 * 152 + ib];              \
          a4 = fmaf(mm.x, xv.x, a4); a4 = fmaf(mm.y, xv.y, a4); }            \
    }

__global__ __launch_bounds__(256, 4) void dwt_gemv(const float* __restrict__ x,
                                                   const float* __restrict__ Mgt,
                                                   float* __restrict__ out) {
    __shared__ float sMt[5 * 152];
    const int tid = threadIdx.x;
    #pragma unroll
    for (int t = 0; t < 3; ++t) {
        const int idx = tid + t * 256;
        if (idx < 760) sMt[idx] = Mgt[idx];
    }
    __syncthreads();

    const size_t g   = (size_t)blockIdx.x * 256 + tid;
    const size_t row = g >> 2;
    const int    q   = (int)(g & 3);
    const float2* __restrict__ xr = (const float2*)(x + row * 150);  // 8B-aligned

    for (int rep = 0; rep < REP; ++rep) {
        // opaque-but-zero LDS index: forces fresh ds_reads each rep (no CSE)
        int base = 0;
        asm volatile("" : "+v"(base));
        // opaque-but-zero accumulator init: forces full fma recompute each rep
        float a0 = 0.f, a1 = 0.f, a2 = 0.f, a3 = 0.f, a4 = 0.f;
        asm volatile("" : "+v"(a0), "+v"(a1), "+v"(a2), "+v"(a3), "+v"(a4));

        // fi = 4j+q for j=0..17 (all quads), plus j=18 for q<3 -> covers 0..74
        #pragma unroll
        for (int j = 0; j < 18; ++j)
            QSTEP(4 * j + q)
        if (q < 3)
            QSTEP(72 + q)

        // quad reduction (lanes 4i..4i+3 in same wave)
        a0 += __shfl_xor(a0, 1); a0 += __shfl_xor(a0, 2);
        a1 += __shfl_xor(a1, 1); a1 += __shfl_xor(a1, 2);
        a2 += __shfl_xor(a2, 1); a2 += __shfl_xor(a2, 2);
        a3 += __shfl_xor(a3, 1); a3 += __shfl_xor(a3, 2);
        a4 += __shfl_xor(a4, 1); a4 += __shfl_xor(a4, 2);

        if (q == 0) {
            float* o = out + row * 5;
            o[0] = a0 + sMt[base + 0 * 152 + 150];
            o[1] = a1 + sMt[base + 1 * 152 + 150];
            o[2] = a2 + sMt[base + 2 * 152 + 150];
            o[3] = a3 + sMt[base + 3 * 152 + 150];
            o[4] = a4 + sMt[base + 4 * 152 + 150];
        }
    }
}

extern "C" void kernel_launch(void* const* d_in, const int* in_sizes, int n_in,
                              void* d_out, int out_size, void* d_ws, size_t ws_size,
                              hipStream_t stream) {
    const float* x    = (const float*)d_in[0];   // (131072, 3, 50)
    const float* W    = (const float*)d_in[1];   // (5, 192)
    const float* bias = (const float*)d_in[2];   // (5,)
    float*       out  = (float*)d_out;           // (131072, 5)
    float*       Mgt  = (float*)d_ws;            // 760 floats, [5][152]

    build_M<<<1, 256, 0, stream>>>(W, bias, Mgt);

    const int B = in_sizes[0] / 150;             // 131072
    const int grid = (B * 4) / 256;              // 2048 blocks, 8/CU
    dwt_gemv<<<grid, 256, 0, stream>>>(x, Mgt, out);
}

// Round 13
// 32.306 us; speedup vs baseline: 2.0175x; 2.0175x over previous
//
#include <hip/hip_runtime.h>

// ---------------------------------------------------------------------------
// Compile-time wavelet-packet response matrix A[64][50].
// ---------------------------------------------------------------------------
struct Amat { float a[64][50]; };

constexpr Amat makeA() {
    constexpr float h0[4] = { 0.48296291314453416f,  0.8365163037378079f,
                              0.22414386804185735f, -0.12940952255126037f};
    constexpr float h1[4] = {-0.12940952255126037f, -0.22414386804185735f,
                              0.8365163037378079f,  -0.48296291314453416f};
    float L1[2][26][50] = {};
    for (int band = 0; band < 2; ++band)
        for (int m = 0; m < 26; ++m)
            for (int n = 0; n < 50; ++n) {
                int k = n - 2 * m + 2;
                L1[band][m][n] = (k >= 0 && k < 4) ? (band ? h1[k] : h0[k]) : 0.0f;
            }
    float L2[4][14][50] = {};
    for (int j = 0; j < 4; ++j)
        for (int m = 0; m < 14; ++m)
            for (int n = 0; n < 50; ++n) {
                float acc = 0.0f;
                for (int k = 0; k < 4; ++k) {
                    int p = 2 * m + k - 2;
                    if (p >= 0 && p < 26)
                        acc += (j & 1 ? h1[k] : h0[k]) * L1[j >> 1][p][n];
                }
                L2[j][m][n] = acc;
            }
    Amat A = {};
    for (int j = 0; j < 8; ++j)
        for (int m = 0; m < 8; ++m)
            for (int n = 0; n < 50; ++n) {
                float acc = 0.0f;
                for (int k = 0; k < 4; ++k) {
                    int p = 2 * m + k - 2;
                    if (p >= 0 && p < 14)
                        acc += (j & 1 ? h1[k] : h0[k]) * L2[j >> 1][p][n];
                }
                A.a[j * 8 + m][n] = acc;
            }
    return A;
}

__device__ __constant__ Amat cA = makeA();

// ---------------------------------------------------------------------------
// Quarter layout (NO out-of-bounds possible):
//   q=0,1,2: source features q*40 + [0,40)
//   q=3    : source features 110 + [0,40)  = 110..149  (max addr = row end!)
// M layout Mg[q*200 + d*5 + k]; for q=3, d<10 (features 110..119, already
// accumulated by q=2) the M entries are ZERO. Bias at Mg[800+k].
// ---------------------------------------------------------------------------
__global__ __launch_bounds__(256) void build_M(const float* __restrict__ W,
                                               const float* __restrict__ bias,
                                               float* __restrict__ Mg) {
    __shared__ float sW[960];
    const int tid = threadIdx.x;
    #pragma unroll
    for (int t = 0; t < 4; ++t) {
        const int idx = tid + t * 256;
        if (idx < 960) sW[idx] = W[idx];
    }
    __syncthreads();

    if (tid < 150) {
        const int c = tid / 50, n = tid - c * 50;
        float m0 = 0.f, m1 = 0.f, m2 = 0.f, m3 = 0.f, m4 = 0.f;
        #pragma unroll 16
        for (int f = 0; f < 64; ++f) {              // f = j*8 + s
            const float av = cA.a[f][n];
            const int wj = (f >> 3) * 24 + c * 8 + (f & 7);
            m0 = fmaf(sW[0 * 192 + wj], av, m0);
            m1 = fmaf(sW[1 * 192 + wj], av, m1);
            m2 = fmaf(sW[2 * 192 + wj], av, m2);
            m3 = fmaf(sW[3 * 192 + wj], av, m3);
            m4 = fmaf(sW[4 * 192 + wj], av, m4);
        }
        // slot: features <120 -> quarter tid/40; features >=120 -> q=3, d=f-110
        const int slot = (tid < 120) ? ((tid / 40) * 200 + (tid % 40) * 5)
                                     : (600 + (tid - 110) * 5);
        float* dst = &Mg[slot];
        dst[0] = m0; dst[1] = m1; dst[2] = m2; dst[3] = m3; dst[4] = m4;
    } else if (tid < 160) {                 // q=3, d = tid-150 in [0,10): M = 0
        float* dst = &Mg[600 + (tid - 150) * 5];
        dst[0] = 0.f; dst[1] = 0.f; dst[2] = 0.f; dst[3] = 0.f; dst[4] = 0.f;
    } else if (tid < 165) {
        Mg[800 + (tid - 160)] = bias[tid - 160];
    }
}

// ---------------------------------------------------------------------------
// Kernel 2: 512 blocks x 256 threads (2 blocks/CU), thread = 1 full row.
// 4 quarters of 40 dwords/row (q=3 overlaps q=2 by 10 zero-weighted feats).
// Per-wave staging of its own 64 rows via 10 w16 global_load_lds per quarter
// -> no barriers; counted vmcnt(10) double-buffer. XOR swizzle applied to
// BOTH staging source and b128 read address (involution, rule #21).
// M via wave-uniform s_load (scalar pipe).
// ---------------------------------------------------------------------------
#define RPB  256
#define QDW  40                   // dwords per row per quarter
#define QBUF (RPB * QDW)          // 10240 dwords per quarter buffer (40 KB)

typedef const __attribute__((address_space(1))) void* gptr_t;
typedef       __attribute__((address_space(3))) void* lptr_t;

__global__ __launch_bounds__(256) void dwt_gemv(const float* __restrict__ x,
                                                const float* __restrict__ Mg,
                                                float* __restrict__ out) {
    extern __shared__ float sX[];        // 2 * QBUF floats (80 KB)
    const int tid  = threadIdx.x;
    const int lane = tid & 63;
    const int w    = tid >> 6;
    const size_t row0 = (size_t)blockIdx.x * RPB;

    // stage quarter qq into buffer buf: this wave covers rows 64w..64w+63
    auto issue = [&](int buf, int qq) {
        const int fbase = (qq < 3) ? qq * 40 : 110;          // source feature base
        #pragma unroll
        for (int s = 0; s < 10; ++s) {
            const int dw = (w * 10 + s) * 256 + lane * 4;    // dword in quarter buf
            const int t  = dw / QDW;                         // row within block
            const int d  = dw - t * QDW;                     // dword within row
            const int vv = ((t ^ (t >> 3)) & 7) << 2;
            const int l  = (d < 32) ? (d ^ vv) : (d ^ (vv & 4));
            const int src = ((int)row0 + t) * 150 + fbase + l;   // ALWAYS in-bounds
            __builtin_amdgcn_global_load_lds((gptr_t)(x + src),
                                             (lptr_t)(sX + buf * QBUF + dw),
                                             16, 0, 0);
        }
    };

    const int t_self = tid;
    const int v_self = ((t_self ^ (t_self >> 3)) & 7) << 2;

    float a0 = 0.f, a1 = 0.f, a2 = 0.f, a3 = 0.f, a4 = 0.f;

    issue(0, 0);

    #pragma unroll
    for (int q = 0; q < 4; ++q) {
        if (q < 3) {
            __builtin_amdgcn_sched_barrier(0);   // pin prior reads above re-stage
            issue((q + 1) & 1, q + 1);
            asm volatile("s_waitcnt vmcnt(10)" ::: "memory");  // q landed, q+1 flying
        } else {
            asm volatile("s_waitcnt vmcnt(0)" ::: "memory");
        }
        __builtin_amdgcn_sched_barrier(0);

        const float* __restrict__ xr = sX + (q & 1) * QBUF + t_self * QDW;
        #pragma unroll
        for (int j = 0; j < 10; ++j) {
            const int d  = 4 * j;
            const int ds = (d < 32) ? (d ^ v_self) : (d ^ (v_self & 4));
            const float4 xv = *(const float4*)&xr[ds];
            const float* m = Mg + q * 200 + d * 5;          // wave-uniform -> s_load
            a0 = fmaf(m[ 0], xv.x, a0);
            a1 = fmaf(m[ 1], xv.x, a1);
            a2 = fmaf(m[ 2], xv.x, a2);
            a3 = fmaf(m[ 3], xv.x, a3);
            a4 = fmaf(m[ 4], xv.x, a4);
            a0 = fmaf(m[ 5], xv.y, a0);
            a1 = fmaf(m[ 6], xv.y, a1);
            a2 = fmaf(m[ 7], xv.y, a2);
            a3 = fmaf(m[ 8], xv.y, a3);
            a4 = fmaf(m[ 9], xv.y, a4);
            a0 = fmaf(m[10], xv.z, a0);
            a1 = fmaf(m[11], xv.z, a1);
            a2 = fmaf(m[12], xv.z, a2);
            a3 = fmaf(m[13], xv.z, a3);
            a4 = fmaf(m[14], xv.z, a4);
            a0 = fmaf(m[15], xv.w, a0);
            a1 = fmaf(m[16], xv.w, a1);
            a2 = fmaf(m[17], xv.w, a2);
            a3 = fmaf(m[18], xv.w, a3);
            a4 = fmaf(m[19], xv.w, a4);
        }
    }

    float* o = out + (row0 + tid) * 5;
    o[0] = a0 + Mg[800];
    o[1] = a1 + Mg[801];
    o[2] = a2 + Mg[802];
    o[3] = a3 + Mg[803];
    o[4] = a4 + Mg[804];
}

extern "C" void kernel_launch(void* const* d_in, const int* in_sizes, int n_in,
                              void* d_out, int out_size, void* d_ws, size_t ws_size,
                              hipStream_t stream) {
    const float* x    = (const float*)d_in[0];   // (131072, 3, 50)
    const float* W    = (const float*)d_in[1];   // (5, 192)
    const float* bias = (const float*)d_in[2];   // (5,)
    float*       out  = (float*)d_out;           // (131072, 5)
    float*       Mg   = (float*)d_ws;            // 805 floats

    build_M<<<1, 256, 0, stream>>>(W, bias, Mg);

    const int B    = in_sizes[0] / 150;          // 131072 rows
    const int grid = B / RPB;                    // 512 blocks (2 per CU)
    const size_t smem = 2 * QBUF * sizeof(float);   // 81920 B dynamic LDS

    (void)hipFuncSetAttribute((const void*)dwt_gemv,
                              hipFuncAttributeMaxDynamicSharedMemorySize,
                              (int)smem);

    dwt_gemv<<<grid, 256, smem, stream>>>(x, Mg, out);
}

// Round 14
// 28.834 us; speedup vs baseline: 2.2605x; 1.1204x over previous
//
#include <hip/hip_runtime.h>

// ---------------------------------------------------------------------------
// Compile-time wavelet-packet response matrix A[64][50].
// ---------------------------------------------------------------------------
struct Amat { float a[64][50]; };

constexpr Amat makeA() {
    constexpr float h0[4] = { 0.48296291314453416f,  0.8365163037378079f,
                              0.22414386804185735f, -0.12940952255126037f};
    constexpr float h1[4] = {-0.12940952255126037f, -0.22414386804185735f,
                              0.8365163037378079f,  -0.48296291314453416f};
    float L1[2][26][50] = {};
    for (int band = 0; band < 2; ++band)
        for (int m = 0; m < 26; ++m)
            for (int n = 0; n < 50; ++n) {
                int k = n - 2 * m + 2;
                L1[band][m][n] = (k >= 0 && k < 4) ? (band ? h1[k] : h0[k]) : 0.0f;
            }
    float L2[4][14][50] = {};
    for (int j = 0; j < 4; ++j)
        for (int m = 0; m < 14; ++m)
            for (int n = 0; n < 50; ++n) {
                float acc = 0.0f;
                for (int k = 0; k < 4; ++k) {
                    int p = 2 * m + k - 2;
                    if (p >= 0 && p < 26)
                        acc += (j & 1 ? h1[k] : h0[k]) * L1[j >> 1][p][n];
                }
                L2[j][m][n] = acc;
            }
    Amat A = {};
    for (int j = 0; j < 8; ++j)
        for (int m = 0; m < 8; ++m)
            for (int n = 0; n < 50; ++n) {
                float acc = 0.0f;
                for (int k = 0; k < 4; ++k) {
                    int p = 2 * m + k - 2;
                    if (p >= 0 && p < 14)
                        acc += (j & 1 ? h1[k] : h0[k]) * L2[j >> 1][p][n];
                }
                A.a[j * 8 + m][n] = acc;
            }
    return A;
}

__device__ __constant__ Amat cA = makeA();

// ---------------------------------------------------------------------------
// Kernel 1 (1 block): fold W (5x192) into Mg[k*160 + i] (i<150; 150..159 = 0),
// bias at Mg[800+k]. Stride 160 keeps reads in-range and bank-regular.
// ---------------------------------------------------------------------------
__global__ __launch_bounds__(256) void build_M(const float* __restrict__ W,
                                               const float* __restrict__ bias,
                                               float* __restrict__ Mg) {
    __shared__ float sW[960];
    const int tid = threadIdx.x;
    #pragma unroll
    for (int t = 0; t < 4; ++t) {
        const int idx = tid + t * 256;
        if (idx < 960) sW[idx] = W[idx];
    }
    __syncthreads();

    if (tid < 150) {
        const int c = tid / 50, n = tid - c * 50;
        float m0 = 0.f, m1 = 0.f, m2 = 0.f, m3 = 0.f, m4 = 0.f;
        #pragma unroll 16
        for (int f = 0; f < 64; ++f) {              // f = j*8 + s
            const float av = cA.a[f][n];
            const int wj = (f >> 3) * 24 + c * 8 + (f & 7);
            m0 = fmaf(sW[0 * 192 + wj], av, m0);
            m1 = fmaf(sW[1 * 192 + wj], av, m1);
            m2 = fmaf(sW[2 * 192 + wj], av, m2);
            m3 = fmaf(sW[3 * 192 + wj], av, m3);
            m4 = fmaf(sW[4 * 192 + wj], av, m4);
        }
        Mg[0 * 160 + tid] = m0;
        Mg[1 * 160 + tid] = m1;
        Mg[2 * 160 + tid] = m2;
        Mg[3 * 160 + tid] = m3;
        Mg[4 * 160 + tid] = m4;
    } else if (tid < 160) {                          // zero pad, all 5 k-rows
        #pragma unroll
        for (int k = 0; k < 5; ++k) Mg[k * 160 + tid] = 0.f;
    } else if (tid < 165) {
        Mg[800 + (tid - 160)] = bias[tid - 160];
    }
}

// ---------------------------------------------------------------------------
// Kernel 2 — CONSUME-ONCE gemv. 16 lanes per row; step j: the 16 lanes read
// 16 consecutive float2 = one contiguous 128B row-segment (a cache line is
// fetched and fully consumed by the same instruction -> no revisits -> FETCH
// = exactly x once). 2 rows per thread (rA, rB = rA+16) share the M-reads.
// Block = 32 rows = 9600 B, 128B-aligned -> zero inter-block line sharing.
// M from LDS: 16 lanes stride 2 dwords = 32 banks exactly once, 4 groups
// broadcast -> conflict-free. 16-lane shfl_xor reduce; funnel store.
// ---------------------------------------------------------------------------
#define RPB2 32                        // rows per block

__global__ __launch_bounds__(256) void dwt_gemv(const float* __restrict__ x,
                                                const float* __restrict__ Mg,
                                                float* __restrict__ out) {
    __shared__ float sM[805];          // [k*160+i] + bias at 800+k
    __shared__ float sO[RPB2 * 5];
    const int tid = threadIdx.x;
    #pragma unroll
    for (int t = 0; t < 4; ++t) {
        const int idx = tid + t * 256;
        if (idx < 805) sM[idx] = Mg[idx];
    }
    __syncthreads();

    const int g  = tid >> 4;           // row-group 0..15
    const int lg = tid & 15;           // lane within group
    const size_t rA = (size_t)blockIdx.x * RPB2 + g;
    const size_t rB = rA + 16;
    const float2* __restrict__ xa = (const float2*)(x + rA * 150);
    const float2* __restrict__ xb = (const float2*)(x + rB * 150);

    float a0 = 0.f, a1 = 0.f, a2 = 0.f, a3 = 0.f, a4 = 0.f;   // row A
    float b0 = 0.f, b1 = 0.f, b2 = 0.f, b3 = 0.f, b4 = 0.f;   // row B

    #pragma unroll
    for (int j = 0; j < 5; ++j) {
        const int fi = j * 16 + lg;                 // float2 index in row
        if (fi < 75) {                              // j<4 always; j==4: lg<11
            const float2 xva = xa[fi];
            const float2 xvb = xb[fi];
            const int d = 2 * fi;
            { const float2 m = *(const float2*)&sM[0 * 160 + d];
              a0 = fmaf(m.x, xva.x, a0); a0 = fmaf(m.y, xva.y, a0);
              b0 = fmaf(m.x, xvb.x, b0); b0 = fmaf(m.y, xvb.y, b0); }
            { const float2 m = *(const float2*)&sM[1 * 160 + d];
              a1 = fmaf(m.x, xva.x, a1); a1 = fmaf(m.y, xva.y, a1);
              b1 = fmaf(m.x, xvb.x, b1); b1 = fmaf(m.y, xvb.y, b1); }
            { const float2 m = *(const float2*)&sM[2 * 160 + d];
              a2 = fmaf(m.x, xva.x, a2); a2 = fmaf(m.y, xva.y, a2);
              b2 = fmaf(m.x, xvb.x, b2); b2 = fmaf(m.y, xvb.y, b2); }
            { const float2 m = *(const float2*)&sM[3 * 160 + d];
              a3 = fmaf(m.x, xva.x, a3); a3 = fmaf(m.y, xva.y, a3);
              b3 = fmaf(m.x, xvb.x, b3); b3 = fmaf(m.y, xvb.y, b3); }
            { const float2 m = *(const float2*)&sM[4 * 160 + d];
              a4 = fmaf(m.x, xva.x, a4); a4 = fmaf(m.y, xva.y, a4);
              b4 = fmaf(m.x, xvb.x, b4); b4 = fmaf(m.y, xvb.y, b4); }
        }
    }

    // reduce within each 16-lane group (xor masks 1,2,4,8 stay in-group)
    #pragma unroll
    for (int o = 1; o < 16; o <<= 1) {
        a0 += __shfl_xor(a0, o); a1 += __shfl_xor(a1, o);
        a2 += __shfl_xor(a2, o); a3 += __shfl_xor(a3, o);
        a4 += __shfl_xor(a4, o);
        b0 += __shfl_xor(b0, o); b1 += __shfl_xor(b1, o);
        b2 += __shfl_xor(b2, o); b3 += __shfl_xor(b3, o);
        b4 += __shfl_xor(b4, o);
    }

    if (lg == 0) {
        float* oa = &sO[g * 5];
        oa[0] = a0 + sM[800]; oa[1] = a1 + sM[801]; oa[2] = a2 + sM[802];
        oa[3] = a3 + sM[803]; oa[4] = a4 + sM[804];
        float* ob = &sO[(g + 16) * 5];
        ob[0] = b0 + sM[800]; ob[1] = b1 + sM[801]; ob[2] = b2 + sM[802];
        ob[3] = b3 + sM[803]; ob[4] = b4 + sM[804];
    }
    __syncthreads();

    if (tid < RPB2 * 5)
        out[(size_t)blockIdx.x * (RPB2 * 5) + tid] = sO[tid];
}

extern "C" void kernel_launch(void* const* d_in, const int* in_sizes, int n_in,
                              void* d_out, int out_size, void* d_ws, size_t ws_size,
                              hipStream_t stream) {
    const float* x    = (const float*)d_in[0];   // (131072, 3, 50)
    const float* W    = (const float*)d_in[1];   // (5, 192)
    const float* bias = (const float*)d_in[2];   // (5,)
    float*       out  = (float*)d_out;           // (131072, 5)
    float*       Mg   = (float*)d_ws;            // 805 floats

    build_M<<<1, 256, 0, stream>>>(W, bias, Mg);

    const int B    = in_sizes[0] / 150;          // 131072 rows
    const int grid = B / RPB2;                   // 4096 blocks
    dwt_gemv<<<grid, 256, 0, stream>>>(x, Mg, out);
}

// Round 16
// 26.516 us; speedup vs baseline: 2.4581x; 1.0874x over previous
//
#include <hip/hip_runtime.h>

// ---------------------------------------------------------------------------
// Compile-time wavelet-packet response matrix A[64][50].
// ---------------------------------------------------------------------------
struct Amat { float a[64][50]; };

constexpr Amat makeA() {
    constexpr float h0[4] = { 0.48296291314453416f,  0.8365163037378079f,
                              0.22414386804185735f, -0.12940952255126037f};
    constexpr float h1[4] = {-0.12940952255126037f, -0.22414386804185735f,
                              0.8365163037378079f,  -0.48296291314453416f};
    float L1[2][26][50] = {};
    for (int band = 0; band < 2; ++band)
        for (int m = 0; m < 26; ++m)
            for (int n = 0; n < 50; ++n) {
                int k = n - 2 * m + 2;
                L1[band][m][n] = (k >= 0 && k < 4) ? (band ? h1[k] : h0[k]) : 0.0f;
            }
    float L2[4][14][50] = {};
    for (int j = 0; j < 4; ++j)
        for (int m = 0; m < 14; ++m)
            for (int n = 0; n < 50; ++n) {
                float acc = 0.0f;
                for (int k = 0; k < 4; ++k) {
                    int p = 2 * m + k - 2;
                    if (p >= 0 && p < 26)
                        acc += (j & 1 ? h1[k] : h0[k]) * L1[j >> 1][p][n];
                }
                L2[j][m][n] = acc;
            }
    Amat A = {};
    for (int j = 0; j < 8; ++j)
        for (int m = 0; m < 8; ++m)
            for (int n = 0; n < 50; ++n) {
                float acc = 0.0f;
                for (int k = 0; k < 4; ++k) {
                    int p = 2 * m + k - 2;
                    if (p >= 0 && p < 14)
                        acc += (j & 1 ? h1[k] : h0[k]) * L2[j >> 1][p][n];
                }
                A.a[j * 8 + m][n] = acc;
            }
    return A;
}

__device__ __constant__ Amat cA = makeA();

// ---------------------------------------------------------------------------
// Kernel 1 (1 block): fold W+bias into step-major layout for the gemv:
//   feature i -> fi = i>>1 (float2 index), p = i&1
//   Mg[fi*10 + k*2 + p] = M[i][k]   (fi in [0,80): slots for fi>=75 are ZERO)
//   Mg[800+k] = bias[k]             (805 floats total)
// ---------------------------------------------------------------------------
__global__ __launch_bounds__(256) void build_M(const float* __restrict__ W,
                                               const float* __restrict__ bias,
                                               float* __restrict__ Mg) {
    __shared__ float sW[960];
    const int tid = threadIdx.x;
    #pragma unroll
    for (int t = 0; t < 4; ++t) {
        const int idx = tid + t * 256;
        if (idx < 960) sW[idx] = W[idx];
    }
    __syncthreads();

    if (tid < 150) {
        const int c = tid / 50, n = tid - c * 50;
        float m0 = 0.f, m1 = 0.f, m2 = 0.f, m3 = 0.f, m4 = 0.f;
        #pragma unroll 16
        for (int f = 0; f < 64; ++f) {              // f = j*8 + s
            const float av = cA.a[f][n];
            const int wj = (f >> 3) * 24 + c * 8 + (f & 7);
            m0 = fmaf(sW[0 * 192 + wj], av, m0);
            m1 = fmaf(sW[1 * 192 + wj], av, m1);
            m2 = fmaf(sW[2 * 192 + wj], av, m2);
            m3 = fmaf(sW[3 * 192 + wj], av, m3);
            m4 = fmaf(sW[4 * 192 + wj], av, m4);
        }
        const int base = (tid >> 1) * 10 + (tid & 1);
        Mg[base + 0] = m0;
        Mg[base + 2] = m1;
        Mg[base + 4] = m2;
        Mg[base + 6] = m3;
        Mg[base + 8] = m4;
    } else if (tid < 160) {                          // pad fi 75..79 -> zero
        const int base = (tid >> 1) * 10 + (tid & 1);
        #pragma unroll
        for (int k = 0; k < 5; ++k) Mg[base + 2 * k] = 0.f;
    } else if (tid < 165) {
        Mg[800 + (tid - 160)] = bias[tid - 160];
    }
}

// ---------------------------------------------------------------------------
// DPP row_ror add: v += rotate-within-16-lane-row(v, N). VALU pipe, no LDS.
// row_ror:N encoding = 0x120+N; rotation-sum over 8,4,2,1 gives all 16 lanes
// the group sum regardless of rotation direction.
// ---------------------------------------------------------------------------
template <int N>
__device__ __forceinline__ float ror_add(float v) {
    const int r = __builtin_amdgcn_update_dpp(
        __float_as_int(v), __float_as_int(v), 0x120 + N, 0xF, 0xF, false);
    return v + __int_as_float(r);
}

// ---------------------------------------------------------------------------
// Kernel 2: 2048 blocks x 256 threads (8/CU, 32 waves/CU). 16 lanes per row,
// 4 rows per thread (rows g, g+16, g+32, g+48 of the block's 64).
// Step s: the 16 lanes read 16 consecutive float2 = one contiguous 128B
// segment per row (consume-once, TA-minimal, proven in R14). The 4 rows
// SHARE each M read -> only 25 ds_read_b64 per thread (6.25/row). Reduce
// across the 16 lanes via DPP ror-adds (VALU pipe — no bpermute, no LDS).
// Tail: x addr clamped to fi=74 (in-bounds), M slots fi>=75 are zero.
// Epilogue: grid-stride store of all 320 outputs (R15 bug: `if tid<320`
// with 256 threads left outputs 256..319 unwritten).
// ---------------------------------------------------------------------------
__global__ __launch_bounds__(256) void dwt_gemv(const float* __restrict__ x,
                                                const float* __restrict__ Mg,
                                                float* __restrict__ out) {
    __shared__ float sM[805];
    __shared__ float sO[64 * 5];
    const int tid = threadIdx.x;
    #pragma unroll
    for (int t = 0; t < 4; ++t) {
        const int idx = tid + t * 256;
        if (idx < 805) sM[idx] = Mg[idx];
    }
    __syncthreads();

    const int g  = tid >> 4;             // group = base row (0..15)
    const int lg = tid & 15;             // lane in group
    const size_t r0 = (size_t)blockIdx.x * 64 + g;
    const float2* __restrict__ xr = (const float2*)x;   // row r starts at r*75

    float a0[5] = {0,0,0,0,0};           // row g
    float a1[5] = {0,0,0,0,0};           // row g+16
    float a2[5] = {0,0,0,0,0};           // row g+32
    float a3[5] = {0,0,0,0,0};           // row g+48

    #pragma unroll
    for (int s = 0; s < 5; ++s) {
        const int fi  = s * 16 + lg;                 // logical float2 index
        const int fx  = (fi < 75) ? fi : 74;         // clamped x index (safe)
        const float2 v0 = xr[(r0     ) * 75 + fx];
        const float2 v1 = xr[(r0 + 16) * 75 + fx];
        const float2 v2 = xr[(r0 + 32) * 75 + fx];
        const float2 v3 = xr[(r0 + 48) * 75 + fx];
        #pragma unroll
        for (int k = 0; k < 5; ++k) {
            const float2 m = *(const float2*)&sM[fi * 10 + k * 2];  // 0 for fi>=75
            a0[k] = fmaf(m.y, v0.y, fmaf(m.x, v0.x, a0[k]));
            a1[k] = fmaf(m.y, v1.y, fmaf(m.x, v1.x, a1[k]));
            a2[k] = fmaf(m.y, v2.y, fmaf(m.x, v2.x, a2[k]));
            a3[k] = fmaf(m.y, v3.y, fmaf(m.x, v3.x, a3[k]));
        }
    }

    // reduce each value across the 16-lane group: VALU-pipe DPP ror-adds
    #pragma unroll
    for (int k = 0; k < 5; ++k) {
        a0[k] = ror_add<1>(ror_add<2>(ror_add<4>(ror_add<8>(a0[k]))));
        a1[k] = ror_add<1>(ror_add<2>(ror_add<4>(ror_add<8>(a1[k]))));
        a2[k] = ror_add<1>(ror_add<2>(ror_add<4>(ror_add<8>(a2[k]))));
        a3[k] = ror_add<1>(ror_add<2>(ror_add<4>(ror_add<8>(a3[k]))));
    }

    if (lg == 0) {
        #pragma unroll
        for (int k = 0; k < 5; ++k) {
            const float b = sM[800 + k];
            sO[(g     ) * 5 + k] = a0[k] + b;
            sO[(g + 16) * 5 + k] = a1[k] + b;
            sO[(g + 32) * 5 + k] = a2[k] + b;
            sO[(g + 48) * 5 + k] = a3[k] + b;
        }
    }
    __syncthreads();

    // coalesced store of ALL 320 outputs with 256 threads (grid-stride)
    for (int idx = tid; idx < 320; idx += 256)
        out[(size_t)blockIdx.x * 320 + idx] = sO[idx];
}

extern "C" void kernel_launch(void* const* d_in, const int* in_sizes, int n_in,
                              void* d_out, int out_size, void* d_ws, size_t ws_size,
                              hipStream_t stream) {
    const float* x    = (const float*)d_in[0];   // (131072, 3, 50)
    const float* W    = (const float*)d_in[1];   // (5, 192)
    const float* bias = (const float*)d_in[2];   // (5,)
    float*       out  = (float*)d_out;           // (131072, 5)
    float*       Mg   = (float*)d_ws;            // 805 floats

    build_M<<<1, 256, 0, stream>>>(W, bias, Mg);

    const int B    = in_sizes[0] / 150;          // 131072 rows
    const int grid = B / 64;                     // 2048 blocks, 8/CU
    dwt_gemv<<<grid, 256, 0, stream>>>(x, Mg, out);
}